// Round 1
// baseline (4225.241 us; speedup 1.0000x reference)
//
#include <hip/hip_runtime.h>
#include <math.h>

// ---------------------------------------------------------------------------
// GlobalSceneEncoder: 4-stage point-transformer encoder, fp32, f64 selections.
// B=4, N0=4096, D=384, K=16.
// ---------------------------------------------------------------------------

#define D384 384

// ---------------- split pts -> pos0, x0 ----------------
__global__ __launch_bounds__(128) void split_kernel(
    const float* __restrict__ pts, float* __restrict__ pos0, float* __restrict__ x0)
{
  const int n = blockIdx.x;
  const int b = blockIdx.y;
  const float* src = pts + ((long)b * 4096 + n) * 387;
  float* pd = pos0 + ((long)b * 4096 + n) * 3;
  float* xd = x0 + ((long)b * 4096 + n) * 384;
  for (int e = threadIdx.x; e < 387; e += 128) {
    float v = src[e];
    if (e < 3) pd[e] = v; else xd[e - 3] = v;
  }
}

// ---------------- FPS: one block per batch, sequential M-1 steps -----------
__global__ __launch_bounds__(1024) void fps_kernel(
    const float* __restrict__ pos, int N, int M,
    int* __restrict__ idx_out, float* __restrict__ pos_out)
{
  const int b = blockIdx.x;
  pos += (long)b * N * 3; idx_out += (long)b * M; pos_out += (long)b * M * 3;
  const int t = threadIdx.x;

  float px[4], py[4], pz[4];
  double dmin[4];
  #pragma unroll
  for (int i = 0; i < 4; i++) {
    const int j = (i << 10) + t;
    if (j < N) { px[i] = pos[j*3]; py[i] = pos[j*3+1]; pz[i] = pos[j*3+2]; dmin[i] = 0.0; }
    else { px[i] = 0.f; py[i] = 0.f; pz[i] = 0.f; dmin[i] = -1.0; }
  }
  const float sxf = pos[0], syf = pos[1], szf = pos[2];
  {
    const double sx = sxf, sy = syf, sz = szf;
    #pragma unroll
    for (int i = 0; i < 4; i++) {
      const int j = (i << 10) + t;
      if (j < N) {
        double dx = (double)px[i]-sx, dy = (double)py[i]-sy, dz = (double)pz[i]-sz;
        dmin[i] = dx*dx + dy*dy + dz*dz;
      }
    }
  }
  if (t == 0) { idx_out[0] = 0; pos_out[0] = sxf; pos_out[1] = syf; pos_out[2] = szf; }

  __shared__ double s_val[16];
  __shared__ int s_idx[16];
  __shared__ int s_sel;

  for (int m = 1; m < M; ++m) {
    double best = -1.0; int bj = 0x7fffffff;
    #pragma unroll
    for (int i = 0; i < 4; i++)
      if (dmin[i] > best) { best = dmin[i]; bj = (i << 10) + t; }
    #pragma unroll
    for (int off = 32; off; off >>= 1) {
      double ov = __shfl_xor(best, off); int oj = __shfl_xor(bj, off);
      if (ov > best || (ov == best && oj < bj)) { best = ov; bj = oj; }
    }
    if ((t & 63) == 0) { s_val[t >> 6] = best; s_idx[t >> 6] = bj; }
    __syncthreads();
    if (t < 16) {
      best = s_val[t]; bj = s_idx[t];
      #pragma unroll
      for (int off = 8; off; off >>= 1) {
        double ov = __shfl_xor(best, off); int oj = __shfl_xor(bj, off);
        if (ov > best || (ov == best && oj < bj)) { best = ov; bj = oj; }
      }
      if (t == 0) s_sel = bj;
    }
    __syncthreads();
    const int sel = s_sel;
    const float qxf = pos[sel*3], qyf = pos[sel*3+1], qzf = pos[sel*3+2];
    const double qx = qxf, qy = qyf, qz = qzf;
    #pragma unroll
    for (int i = 0; i < 4; i++) {
      const int j = (i << 10) + t;
      if (j < N) {
        double dx = (double)px[i]-qx, dy = (double)py[i]-qy, dz = (double)pz[i]-qz;
        double dd = dx*dx + dy*dy + dz*dz;
        if (dd < dmin[i]) dmin[i] = dd;
      }
    }
    if (t == 0) { idx_out[m] = sel; pos_out[m*3] = qxf; pos_out[m*3+1] = qyf; pos_out[m*3+2] = qzf; }
  }
}

// ---------------- KNN: one wave per query, 16 lexicographic-min passes -----
template<int C>
__global__ __launch_bounds__(64) void knn_kernel(
    const float* __restrict__ pos, const float* __restrict__ qpos,
    int N, int M, int* __restrict__ nbr, float* __restrict__ vld, double r2)
{
  const int m = blockIdx.x, b = blockIdx.y;
  pos += (long)b * N * 3; qpos += (long)b * M * 3;
  nbr += (long)b * (1024 * 16); vld += (long)b * (1024 * 16);
  const int lane = threadIdx.x;
  const double qx = qpos[m*3], qy = qpos[m*3+1], qz = qpos[m*3+2];
  double d[C];
  #pragma unroll
  for (int c = 0; c < C; c++) {
    const int j = c * 64 + lane;
    double dx = (double)pos[j*3] - qx;
    double dy = (double)pos[j*3+1] - qy;
    double dz = (double)pos[j*3+2] - qz;
    d[c] = dx*dx + dy*dy + dz*dz;
  }
  double pd = -1.0; int pj = -1;
  for (int k = 0; k < 16; k++) {
    double best = 1e300; int bj = 0x7fffffff;
    #pragma unroll
    for (int c = 0; c < C; c++) {
      const int j = c * 64 + lane;
      const bool after = (d[c] > pd) || (d[c] == pd && j > pj);
      if (after && d[c] < best) { best = d[c]; bj = j; }
    }
    #pragma unroll
    for (int off = 32; off; off >>= 1) {
      double ov = __shfl_xor(best, off); int oj = __shfl_xor(bj, off);
      if (ov < best || (ov == best && oj < bj)) { best = ov; bj = oj; }
    }
    pd = best; pj = bj;
    if (lane == 0) { nbr[m*16+k] = bj; vld[m*16+k] = (best <= r2) ? 1.0f : 0.0f; }
  }
}

// ---------------- fp32 tiled GEMM, 64x64x16, 3 A-operand modes -------------
// AMODE 0: A = rows of p.A (optional gather)     -> v / a_src / a_dst
// AMODE 1: A = relu(rel @ pw1 + pb1) on the fly  -> delta GEMM
// AMODE 2: A = a_dst[m] - a_src[nbr] + delta     -> alpha GEMM
struct GemmP {
  const float* A; long sA;
  const float* W;
  const float* bias;
  float* C; long sC;
  int R;
  const int* gather; long sG;
  const float* qpos; long sQ;
  const float* pos;  long sP;
  const int* nbr;    long sN;
  const float* pw1;
  const float* pb1;
  const float* adst; long sAD;
  const float* asrc; long sAS;
  int row0;
};

template<int AMODE, bool GATHER, bool BIAS, bool RELU>
__global__ __launch_bounds__(256) void gemm_kernel(GemmP p)
{
  const int b = blockIdx.z;
  const int rb = blockIdx.x * 64;
  const int cb = blockIdx.y * 64;
  const int t = threadIdx.x;
  const float* A = p.A ? (p.A + (long)b * p.sA) : nullptr;
  float* C = p.C + (long)b * p.sC;
  const int* gat = GATHER ? (p.gather + (long)b * p.sG) : nullptr;
  const int* nbrb = (AMODE != 0) ? (p.nbr + (long)b * p.sN) : nullptr;
  const float* qposb = (AMODE == 1) ? (p.qpos + (long)b * p.sQ) : nullptr;
  const float* posb  = (AMODE == 1) ? (p.pos + (long)b * p.sP) : nullptr;
  const float* adstb = (AMODE == 2) ? (p.adst + (long)b * p.sAD) : nullptr;
  const float* asrcb = (AMODE == 2) ? (p.asrc + (long)b * p.sAS) : nullptr;

  __shared__ float As[16][68];
  __shared__ float Bs[16][68];

  const int ty = t >> 4, tx = t & 15;
  float acc[4][4];
  #pragma unroll
  for (int i = 0; i < 4; i++)
    #pragma unroll
    for (int j = 0; j < 4; j++) acc[i][j] = 0.f;

  const int ar = rb + (t >> 2);
  const int acoff = (t & 3) << 2;

  for (int k0 = 0; k0 < 384; k0 += 16) {
    const int ac = k0 + acoff;
    float4 av;
    if (AMODE == 0) {
      if (ar < p.R) {
        const long src = GATHER ? (long)gat[ar] : (long)ar;
        av = *(const float4*)(A + src * 384 + ac);
      } else av = make_float4(0.f, 0.f, 0.f, 0.f);
    } else if (AMODE == 1) {
      const int grow = p.row0 + ar;
      const int mq = grow >> 4;
      const int n = nbrb[grow];
      const float rx = qposb[mq*3+0] - posb[n*3+0];
      const float ry = qposb[mq*3+1] - posb[n*3+1];
      const float rz = qposb[mq*3+2] - posb[n*3+2];
      const float4 w0 = *(const float4*)(p.pw1 + ac);
      const float4 w1 = *(const float4*)(p.pw1 + 384 + ac);
      const float4 w2 = *(const float4*)(p.pw1 + 768 + ac);
      const float4 b1 = *(const float4*)(p.pb1 + ac);
      av.x = fmaxf(rx*w0.x + ry*w1.x + rz*w2.x + b1.x, 0.f);
      av.y = fmaxf(rx*w0.y + ry*w1.y + rz*w2.y + b1.y, 0.f);
      av.z = fmaxf(rx*w0.z + ry*w1.z + rz*w2.z + b1.z, 0.f);
      av.w = fmaxf(rx*w0.w + ry*w1.w + rz*w2.w + b1.w, 0.f);
    } else {
      const int grow = p.row0 + ar;
      const int mq = grow >> 4;
      const int n = nbrb[grow];
      const float4 dd = *(const float4*)(A + (long)ar * 384 + ac);
      const float4 a4 = *(const float4*)(adstb + (long)mq * 384 + ac);
      const float4 s4 = *(const float4*)(asrcb + (long)n * 384 + ac);
      av.x = a4.x - s4.x + dd.x;
      av.y = a4.y - s4.y + dd.y;
      av.z = a4.z - s4.z + dd.z;
      av.w = a4.w - s4.w + dd.w;
    }
    As[acoff + 0][t >> 2] = av.x;
    As[acoff + 1][t >> 2] = av.y;
    As[acoff + 2][t >> 2] = av.z;
    As[acoff + 3][t >> 2] = av.w;

    const float4 wv = *(const float4*)(p.W + (long)(k0 + (t >> 4)) * 384 + cb + ((t & 15) << 2));
    *(float4*)&Bs[t >> 4][(t & 15) << 2] = wv;
    __syncthreads();

    #pragma unroll
    for (int kk = 0; kk < 16; kk++) {
      const float4 a4 = *(const float4*)&As[kk][ty << 2];
      const float4 b4 = *(const float4*)&Bs[kk][tx << 2];
      const float aa[4] = {a4.x, a4.y, a4.z, a4.w};
      const float bb[4] = {b4.x, b4.y, b4.z, b4.w};
      #pragma unroll
      for (int i = 0; i < 4; i++)
        #pragma unroll
        for (int j = 0; j < 4; j++)
          acc[i][j] = fmaf(aa[i], bb[j], acc[i][j]);
    }
    __syncthreads();
  }

  float4 bi = make_float4(0.f, 0.f, 0.f, 0.f);
  if (BIAS) bi = *(const float4*)(p.bias + cb + (tx << 2));
  #pragma unroll
  for (int i = 0; i < 4; i++) {
    const int r = rb + (ty << 2) + i;
    if (r < p.R) {
      float4 o;
      o.x = acc[i][0] + bi.x; o.y = acc[i][1] + bi.y;
      o.z = acc[i][2] + bi.z; o.w = acc[i][3] + bi.w;
      if (RELU) { o.x = fmaxf(o.x, 0.f); o.y = fmaxf(o.y, 0.f); o.z = fmaxf(o.z, 0.f); o.w = fmaxf(o.w, 0.f); }
      *(float4*)(C + (long)r * 384 + cb + (tx << 2)) = o;
    }
  }
}

// ---------------- masked softmax over K + weighted sum + LayerNorm ---------
__global__ __launch_bounds__(128) void attnln_kernel(
    const float* __restrict__ alpha, const float* __restrict__ delta,
    const float* __restrict__ vbuf, const int* __restrict__ nbr,
    const float* __restrict__ vldb, const float* __restrict__ lng,
    const float* __restrict__ lnb, float* __restrict__ xout,
    int q0, long sCh, long sV, long sNb, long sX)
{
  const int ml = blockIdx.x, b = blockIdx.y;
  const int m = q0 + ml;
  alpha += (long)b * sCh; delta += (long)b * sCh; vbuf += (long)b * sV;
  nbr += (long)b * sNb; vldb += (long)b * sNb; xout += (long)b * sX;
  const int t = threadIdx.x;

  int nb[16]; float vl[16];
  #pragma unroll
  for (int k = 0; k < 16; k++) { nb[k] = nbr[m*16+k]; vl[k] = vldb[m*16+k]; }

  const long rbase = (long)ml * 16 * 384;
  float av[16][3];
  #pragma unroll
  for (int k = 0; k < 16; k++)
    #pragma unroll
    for (int i = 0; i < 3; i++) {
      const float a = alpha[rbase + k*384 + t + i*128];
      av[k][i] = (vl[k] > 0.5f) ? a : -1e30f;
    }
  float mx[3] = {-3.4e38f, -3.4e38f, -3.4e38f};
  #pragma unroll
  for (int k = 0; k < 16; k++)
    #pragma unroll
    for (int i = 0; i < 3; i++) mx[i] = fmaxf(mx[i], av[k][i]);
  float sm[3] = {0.f, 0.f, 0.f};
  #pragma unroll
  for (int k = 0; k < 16; k++)
    #pragma unroll
    for (int i = 0; i < 3; i++) { const float e = expf(av[k][i] - mx[i]); av[k][i] = e; sm[i] += e; }
  float rs[3];
  #pragma unroll
  for (int i = 0; i < 3; i++) rs[i] = 1.0f / sm[i];
  float o[3] = {0.f, 0.f, 0.f};
  #pragma unroll
  for (int k = 0; k < 16; k++) {
    const long nrow = (long)nb[k] * 384;
    #pragma unroll
    for (int i = 0; i < 3; i++) {
      const int dd = t + i * 128;
      const float vv = vbuf[nrow + dd] + delta[rbase + k*384 + dd];
      o[i] += (av[k][i] * rs[i] * vl[k]) * vv;
    }
  }
  // LayerNorm over 384
  __shared__ float sred[2];
  float s1 = o[0] + o[1] + o[2];
  #pragma unroll
  for (int off = 32; off; off >>= 1) s1 += __shfl_xor(s1, off);
  if ((t & 63) == 0) sred[t >> 6] = s1;
  __syncthreads();
  const float mean = (sred[0] + sred[1]) * (1.0f / 384.0f);
  __syncthreads();
  float s2 = 0.f;
  #pragma unroll
  for (int i = 0; i < 3; i++) { const float dd = o[i] - mean; s2 += dd * dd; }
  #pragma unroll
  for (int off = 32; off; off >>= 1) s2 += __shfl_xor(s2, off);
  if ((t & 63) == 0) sred[t >> 6] = s2;
  __syncthreads();
  const float var = (sred[0] + sred[1]) * (1.0f / 384.0f);
  const float rstd = 1.0f / sqrtf(var + 1e-5f);
  #pragma unroll
  for (int i = 0; i < 3; i++) {
    const int dd = t + i * 128;
    xout[(long)m * 384 + dd] = (o[i] - mean) * rstd * lng[dd] + lnb[dd];
  }
}

// ---------------- final projection + LayerNorm -----------------------------
__global__ __launch_bounds__(384) void feat_kernel(
    const float* __restrict__ x4, const float* __restrict__ pw,
    const float* __restrict__ pb, const float* __restrict__ g,
    const float* __restrict__ be, float* __restrict__ outf)
{
  const int row = blockIdx.x, b = blockIdx.y;
  const long r = (long)b * 16 + row;
  const int d = threadIdx.x;
  __shared__ float xs[384];
  xs[d] = x4[r * 384 + d];
  __syncthreads();
  float acc = pb[d];
  #pragma unroll 8
  for (int j = 0; j < 384; j++) acc = fmaf(xs[j], pw[(long)j * 384 + d], acc);
  __shared__ float sred[6];
  float s = acc;
  #pragma unroll
  for (int off = 32; off; off >>= 1) s += __shfl_xor(s, off);
  if ((d & 63) == 0) sred[d >> 6] = s;
  __syncthreads();
  const float mean = (sred[0]+sred[1]+sred[2]+sred[3]+sred[4]+sred[5]) * (1.0f/384.0f);
  __syncthreads();
  float dv = (acc - mean) * (acc - mean);
  #pragma unroll
  for (int off = 32; off; off >>= 1) dv += __shfl_xor(dv, off);
  if ((d & 63) == 0) sred[d >> 6] = dv;
  __syncthreads();
  const float var = (sred[0]+sred[1]+sred[2]+sred[3]+sred[4]+sred[5]) * (1.0f/384.0f);
  const float rstd = 1.0f / sqrtf(var + 1e-5f);
  outf[r * 384 + d] = (acc - mean) * rstd * g[d] + be[d];
}

// ---------------- pos + pad outputs ----------------------------------------
__global__ void tail_kernel(const float* __restrict__ p4, float* __restrict__ out)
{
  const int t = threadIdx.x;
  if (t < 192) out[t] = p4[t];
  if (t < 64) out[192 + 24576 + t] = 0.0f;
}

// ---------------------------------------------------------------------------
extern "C" void kernel_launch(void* const* d_in, const int* in_sizes, int n_in,
                              void* d_out, int out_size, void* d_ws, size_t ws_size,
                              hipStream_t stream)
{
  (void)in_sizes; (void)n_in; (void)out_size; (void)ws_size;
  const float* pts    = (const float*)d_in[0];
  const float* lin_w  = (const float*)d_in[1];
  const float* lin_b  = (const float*)d_in[2];
  const float* src_w  = (const float*)d_in[3];
  const float* dst_w  = (const float*)d_in[4];
  const float* pos_w1 = (const float*)d_in[5];
  const float* pos_b1 = (const float*)d_in[6];
  const float* pos_w2 = (const float*)d_in[7];
  const float* pos_b2 = (const float*)d_in[8];
  const float* attn_w = (const float*)d_in[9];
  const float* attn_b = (const float*)d_in[10];
  const float* ln_g   = (const float*)d_in[11];
  const float* ln_b   = (const float*)d_in[12];
  const float* proj_w = (const float*)d_in[13];
  const float* proj_b = (const float*)d_in[14];
  const float* pln_g  = (const float*)d_in[15];
  const float* pln_b  = (const float*)d_in[16];
  float* out = (float*)d_out;

  // ---- workspace layout (floats) ----
  constexpr long SX0 = 4096L*384, SX1 = 1024L*384, SX2 = 256L*384, SX3 = 64L*384, SX4 = 16L*384;
  constexpr long SP0 = 4096L*3, SP1 = 1024L*3, SP2 = 256L*3, SP3 = 64L*3, SP4 = 16L*3;
  constexpr long SV  = 4096L*384;   // v / a_src per-batch stride
  constexpr long SAD = 1024L*384;   // a_dst per-batch stride
  constexpr long SCH = 4096L*384;   // delta/alpha chunk per-batch stride
  constexpr long SNB = 1024L*16;    // nbr / valid per-batch stride

  float* ws = (float*)d_ws;
  float* x0 = ws; ws += 4*SX0;
  float* x1 = ws; ws += 4*SX1;
  float* x2 = ws; ws += 4*SX2;
  float* x3 = ws; ws += 4*SX3;
  float* x4 = ws; ws += 4*SX4;
  float* p0 = ws; ws += 4*SP0;
  float* p1 = ws; ws += 4*SP1;
  float* p2 = ws; ws += 4*SP2;
  float* p3 = ws; ws += 4*SP3;
  float* p4 = ws; ws += 4*SP4;
  float* vb = ws; ws += 4*SV;
  float* asb = ws; ws += 4*SV;
  float* adb = ws; ws += 4*SAD;
  float* db = ws; ws += 4*SCH;
  float* ab = ws; ws += 4*SCH;
  float* vld = ws; ws += 4*SNB;
  int* nb = (int*)ws; ws += 4*SNB;
  int* ix[4];
  ix[0] = (int*)ws; ws += 4*1024;
  ix[1] = (int*)ws; ws += 4*256;
  ix[2] = (int*)ws; ws += 4*64;
  ix[3] = (int*)ws; ws += 4*16;

  const int Ns[4] = {4096, 1024, 256, 64};
  const int Ms[4] = {1024, 256, 64, 16};
  const double R2[4] = {1.0, 4.0, 16.0, 64.0};
  float* X[5] = {x0, x1, x2, x3, x4};
  float* P[5] = {p0, p1, p2, p3, p4};
  long SXs[5] = {SX0, SX1, SX2, SX3, SX4};
  long SPs[5] = {SP0, SP1, SP2, SP3, SP4};

  // split pts
  split_kernel<<<dim3(4096, 4), 128, 0, stream>>>(pts, p0, x0);

  // FPS chain (depends only on positions)
  for (int s = 0; s < 4; s++)
    fps_kernel<<<dim3(4), 1024, 0, stream>>>(P[s], Ns[s], Ms[s], ix[s], P[s+1]);

  for (int s = 0; s < 4; s++) {
    const int N = Ns[s], M = Ms[s];
    // KNN
    switch (s) {
      case 0: knn_kernel<64><<<dim3(M, 4), 64, 0, stream>>>(P[s], P[s+1], N, M, nb, vld, R2[s]); break;
      case 1: knn_kernel<16><<<dim3(M, 4), 64, 0, stream>>>(P[s], P[s+1], N, M, nb, vld, R2[s]); break;
      case 2: knn_kernel<4><<<dim3(M, 4), 64, 0, stream>>>(P[s], P[s+1], N, M, nb, vld, R2[s]); break;
      default: knn_kernel<1><<<dim3(M, 4), 64, 0, stream>>>(P[s], P[s+1], N, M, nb, vld, R2[s]); break;
    }
    // v = x@lw + lb
    {
      GemmP g{}; g.A = X[s]; g.sA = SXs[s]; g.W = lin_w + (long)s*147456; g.bias = lin_b + (long)s*384;
      g.C = vb; g.sC = SV; g.R = N;
      gemm_kernel<0, false, true, false><<<dim3(N/64, 6, 4), 256, 0, stream>>>(g);
    }
    // a_src = x@sw
    {
      GemmP g{}; g.A = X[s]; g.sA = SXs[s]; g.W = src_w + (long)s*147456;
      g.C = asb; g.sC = SV; g.R = N;
      gemm_kernel<0, false, false, false><<<dim3(N/64, 6, 4), 256, 0, stream>>>(g);
    }
    // a_dst = x[idx]@dw
    {
      GemmP g{}; g.A = X[s]; g.sA = SXs[s]; g.W = dst_w + (long)s*147456;
      g.C = adb; g.sC = SAD; g.R = M; g.gather = ix[s]; g.sG = M;
      gemm_kernel<0, true, false, false><<<dim3((M+63)/64, 6, 4), 256, 0, stream>>>(g);
    }
    // chunks of 256 queries: delta GEMM, alpha GEMM, softmax+LN
    const int nch = (M + 255) / 256;
    for (int c = 0; c < nch; c++) {
      const int q0 = c * 256;
      const int Mc = (M - q0 < 256) ? (M - q0) : 256;
      const int rows = Mc * 16;
      {
        GemmP g{}; g.W = pos_w2 + (long)s*147456; g.bias = pos_b2 + (long)s*384;
        g.C = db; g.sC = SCH; g.R = rows;
        g.qpos = P[s+1]; g.sQ = SPs[s+1]; g.pos = P[s]; g.sP = SPs[s];
        g.nbr = nb; g.sN = SNB; g.pw1 = pos_w1 + (long)s*1152; g.pb1 = pos_b1 + (long)s*384;
        g.row0 = q0 * 16;
        gemm_kernel<1, false, true, true><<<dim3(rows/64, 6, 4), 256, 0, stream>>>(g);
      }
      {
        GemmP g{}; g.A = db; g.sA = SCH; g.W = attn_w + (long)s*147456; g.bias = attn_b + (long)s*384;
        g.C = ab; g.sC = SCH; g.R = rows;
        g.nbr = nb; g.sN = SNB; g.adst = adb; g.sAD = SAD; g.asrc = asb; g.sAS = SV;
        g.row0 = q0 * 16;
        gemm_kernel<2, false, true, true><<<dim3(rows/64, 6, 4), 256, 0, stream>>>(g);
      }
      attnln_kernel<<<dim3(Mc, 4), 128, 0, stream>>>(
          ab, db, vb, nb, vld, ln_g + (long)s*384, ln_b + (long)s*384,
          X[s+1], q0, SCH, SV, SNB, (long)M*384);
    }
  }

  feat_kernel<<<dim3(16, 4), 384, 0, stream>>>(x4, proj_w, proj_b, pln_g, pln_b, out + 192);
  tail_kernel<<<1, 256, 0, stream>>>(p4, out);
}